// Round 1
// baseline (27552.451 us; speedup 1.0000x reference)
//
#include <hip/hip_runtime.h>
#include <cstddef>

// Problem constants
#define TT 512
#define BB 64
#define EE 512
#define N3 1536   // 3*EE

// ---------------------------------------------------------------------------
// Embedding gather: xout[i][:] = emb[idx[i]][:], i = t*B+b
// ---------------------------------------------------------------------------
__global__ void embed_k(const int* __restrict__ idx, const float* __restrict__ emb,
                        float* __restrict__ xout) {
    const int i = blockIdx.x;                 // 0..T*B-1
    const int row = idx[i];
    const float4* s = (const float4*)(emb + (size_t)row * EE);
    float4* d = (float4*)(xout + (size_t)i * EE);
    d[threadIdx.x] = s[threadIdx.x];          // 128 threads * float4 = 512 floats
}

// ---------------------------------------------------------------------------
// x_proj GEMM: C[M][N] = A[M][K] * W[N][K]^T + bias[N]
// M=32768, N=1536, K=512. 128x128 tile, 8x8 per thread, fp32.
// ---------------------------------------------------------------------------
__global__ __launch_bounds__(256)
void gemm_xp(const float* __restrict__ A, const float* __restrict__ W,
             const float* __restrict__ bias, float* __restrict__ C) {
    constexpr int K = EE, N = N3;
    __shared__ float As[16][132];
    __shared__ float Bs[16][132];
    const int tid = threadIdx.x;
    const int tx = tid & 15, ty = tid >> 4;
    const int m0 = blockIdx.y * 128, n0 = blockIdx.x * 128;
    const int r = tid >> 1;            // 0..127
    const int kq = (tid & 1) * 8;      // 0 or 8
    const float* Ap = A + (size_t)(m0 + r) * K + kq;
    const float* Wp = W + (size_t)(n0 + r) * K + kq;

    float acc[8][8];
#pragma unroll
    for (int i = 0; i < 8; ++i)
#pragma unroll
        for (int j = 0; j < 8; ++j) acc[i][j] = 0.f;

    for (int k0 = 0; k0 < K; k0 += 16) {
        float4 a0 = *(const float4*)(Ap + k0);
        float4 a1 = *(const float4*)(Ap + k0 + 4);
        float4 b0 = *(const float4*)(Wp + k0);
        float4 b1 = *(const float4*)(Wp + k0 + 4);
        __syncthreads();
        As[kq+0][r] = a0.x; As[kq+1][r] = a0.y; As[kq+2][r] = a0.z; As[kq+3][r] = a0.w;
        As[kq+4][r] = a1.x; As[kq+5][r] = a1.y; As[kq+6][r] = a1.z; As[kq+7][r] = a1.w;
        Bs[kq+0][r] = b0.x; Bs[kq+1][r] = b0.y; Bs[kq+2][r] = b0.z; Bs[kq+3][r] = b0.w;
        Bs[kq+4][r] = b1.x; Bs[kq+5][r] = b1.y; Bs[kq+6][r] = b1.z; Bs[kq+7][r] = b1.w;
        __syncthreads();
#pragma unroll
        for (int kk = 0; kk < 16; ++kk) {
            float av[8], bv[8];
            *(float4*)&av[0] = *(const float4*)&As[kk][ty*8];
            *(float4*)&av[4] = *(const float4*)&As[kk][ty*8+4];
            *(float4*)&bv[0] = *(const float4*)&Bs[kk][tx*8];
            *(float4*)&bv[4] = *(const float4*)&Bs[kk][tx*8+4];
#pragma unroll
            for (int i = 0; i < 8; ++i)
#pragma unroll
                for (int j = 0; j < 8; ++j)
                    acc[i][j] += av[i] * bv[j];
        }
    }
#pragma unroll
    for (int i = 0; i < 8; ++i) {
        float* Crow = C + (size_t)(m0 + ty*8 + i) * N + n0 + tx*8;
#pragma unroll
        for (int j = 0; j < 8; ++j)
            Crow[j] = acc[i][j] + bias[n0 + tx*8 + j];
    }
}

// ---------------------------------------------------------------------------
// Two-level grid barrier, monotonic epochs (no reset needed across launches).
// ctrl[g*32] : per-group counters (8 groups of 32 blocks), ctrl[256]: global.
// ---------------------------------------------------------------------------
__device__ __forceinline__ void grid_barrier(unsigned* ctrl, unsigned e) {
    __syncthreads();
    if (threadIdx.x == 0) {
        __threadfence();   // agent release: wb L2 so other XCDs see h writes
        unsigned* gcnt = ctrl + (blockIdx.x & 7u) * 32;
        unsigned* gl = ctrl + 256;
        unsigned a = __hip_atomic_fetch_add(gcnt, 1u, __ATOMIC_RELEASE,
                                            __HIP_MEMORY_SCOPE_AGENT);
        if (a == 32u * e - 1u)
            __hip_atomic_fetch_add(gl, 1u, __ATOMIC_RELEASE,
                                   __HIP_MEMORY_SCOPE_AGENT);
        while (__hip_atomic_load(gl, __ATOMIC_RELAXED,
                                 __HIP_MEMORY_SCOPE_AGENT) < 8u * e)
            __builtin_amdgcn_s_sleep(2);
        __threadfence();   // agent acquire: inv L1/L2 before reading new h
    }
    __syncthreads();
}

// ---------------------------------------------------------------------------
// GRU recurrence for one layer. 256 blocks x 256 threads, persistent.
// Block owns e-slice [2*blk, 2*blk+2) -> 6 Whh rows (r,z,n x 2) kept in VGPRs.
// Thread (bt = tid>>4, kc = tid&15): batches 4*bt..+3, k-chunk kc*32..+31.
// h ping-pongs between hA/hB in global memory; grid barrier per step.
// ---------------------------------------------------------------------------
__global__ __launch_bounds__(256, 1)
void gru_scan(const float* __restrict__ xp,   // [T][B][3E] (includes b_ih)
              const float* __restrict__ Whh,  // [3E][E] this layer
              const float* __restrict__ bhh,  // [3E]   this layer
              const int* __restrict__ lens,   // [B]
              float* __restrict__ y,          // [T][B][E]
              float* __restrict__ hA, float* __restrict__ hB,  // [B][E] each
              float* __restrict__ finals,     // [B][E]
              unsigned* __restrict__ ctrl, unsigned ebase)
{
    const int e0 = blockIdx.x * 2;
    const int tid = threadIdx.x;
    const int kc = tid & 15;
    const int bt = tid >> 4;
    const int kbase = kc * 32;

    // weights in registers: w[c][k], c = {r0,r1,z0,z1,n0,n1}
    float w[6][32];
#pragma unroll
    for (int c = 0; c < 6; ++c) {
        const int row = (c >> 1) * EE + e0 + (c & 1);
        const float4* wp = (const float4*)(Whh + (size_t)row * EE + kbase);
#pragma unroll
        for (int q = 0; q < 8; ++q) {
            float4 v = wp[q];
            w[c][q*4+0] = v.x; w[c][q*4+1] = v.y;
            w[c][q*4+2] = v.z; w[c][q*4+3] = v.w;
        }
    }
    float bh[6];
#pragma unroll
    for (int c = 0; c < 6; ++c) bh[c] = bhh[(c >> 1) * EE + e0 + (c & 1)];
    int mylen[4];
#pragma unroll
    for (int bi = 0; bi < 4; ++bi) mylen[bi] = lens[bt * 4 + bi];
    float hreg[4][2] = {{0.f, 0.f}, {0.f, 0.f}, {0.f, 0.f}, {0.f, 0.f}};

    for (int t = 0; t < TT; ++t) {
        const float* hc = (t & 1) ? hB : hA;
        float* hn = (t & 1) ? hA : hB;

        float acc[6][4];
#pragma unroll
        for (int c = 0; c < 6; ++c)
#pragma unroll
            for (int bi = 0; bi < 4; ++bi) acc[c][bi] = 0.f;

#pragma unroll
        for (int bi = 0; bi < 4; ++bi) {
            const float4* hp = (const float4*)(hc + (size_t)(bt*4 + bi) * EE + kbase);
#pragma unroll
            for (int q = 0; q < 8; ++q) {
                float4 hv = hp[q];
#pragma unroll
                for (int c = 0; c < 6; ++c) {
                    acc[c][bi] += w[c][q*4+0]*hv.x + w[c][q*4+1]*hv.y
                                + w[c][q*4+2]*hv.z + w[c][q*4+3]*hv.w;
                }
            }
        }
        // reduce partial dots across the 16 kc lanes (lane bits 0..3)
#pragma unroll
        for (int m = 1; m < 16; m <<= 1) {
#pragma unroll
            for (int c = 0; c < 6; ++c)
#pragma unroll
                for (int bi = 0; bi < 4; ++bi)
                    acc[c][bi] += __shfl_xor(acc[c][bi], m, 64);
        }

        if (kc == 0) {
#pragma unroll
            for (int bi = 0; bi < 4; ++bi) {
                const int b = bt * 4 + bi;
                const bool msk = (t < mylen[bi]);
                const float* xpb = xp + ((size_t)t * BB + b) * N3;
#pragma unroll
                for (int ei = 0; ei < 2; ++ei) {
                    const int e = e0 + ei;
                    const float xr = xpb[e], xz = xpb[EE + e], xn = xpb[2*EE + e];
                    const float hr = acc[0+ei][bi] + bh[0+ei];
                    const float hz = acc[2+ei][bi] + bh[2+ei];
                    const float hv = acc[4+ei][bi] + bh[4+ei];
                    const float rg = 1.f / (1.f + __expf(-(xr + hr)));
                    const float zg = 1.f / (1.f + __expf(-(xz + hz)));
                    const float ng = tanhf(xn + rg * hv);
                    const float hold = hreg[bi][ei];
                    const float hnew = (1.f - zg) * ng + zg * hold;
                    const float hout = msk ? hnew : hold;
                    hreg[bi][ei] = hout;
                    hn[(size_t)b * EE + e] = hout;
                    y[((size_t)t * BB + b) * EE + e] = msk ? hout : 0.f;
                    if (t == TT - 1) finals[(size_t)b * EE + e] = hout;
                }
            }
        }
        grid_barrier(ctrl, ebase + (unsigned)t + 1u);
    }
}

// ---------------------------------------------------------------------------
extern "C" void kernel_launch(void* const* d_in, const int* in_sizes, int n_in,
                              void* d_out, int out_size, void* d_ws, size_t ws_size,
                              hipStream_t stream) {
    const int* input_batch  = (const int*)d_in[0];
    const int* lens         = (const int*)d_in[1];
    const float* emb        = (const float*)d_in[2];
    const float* W_ih       = (const float*)d_in[3];
    const float* W_hh       = (const float*)d_in[4];
    const float* b_ih       = (const float*)d_in[5];
    const float* b_hh       = (const float*)d_in[6];
    float* out = (float*)d_out;
    float* ws  = (float*)d_ws;

    // workspace layout (float offsets)
    const size_t XPROJ = 0;                          // [T][B][3E] = 50331648
    const size_t XBUF  = (size_t)TT * BB * N3;       // x_emb, then ys0: 16777216
    const size_t H0    = XBUF + (size_t)TT * BB * EE;
    const size_t H1    = H0 + (size_t)BB * EE;
    const size_t CTRL  = H1 + (size_t)BB * EE;
    if (ws_size < (CTRL + 512) * sizeof(float)) return;  // ~269 MB needed

    float* xproj = ws + XPROJ;
    float* xbuf  = ws + XBUF;
    float* h0    = ws + H0;
    float* h1    = ws + H1;
    unsigned* ctrl = (unsigned*)(ws + CTRL);

    const size_t OUT_YS = 0;                              // [T][B][E]
    const size_t OUT_FIN = (size_t)TT * BB * EE;          // [L][B][E]

    // zero h ping-pong buffers + barrier control (ws is poisoned 0xAA)
    hipMemsetAsync(h0, 0, (2 * (size_t)BB * EE + 512) * sizeof(float), stream);

    // x = emb[input_batch]
    embed_k<<<dim3(TT * BB), dim3(128), 0, stream>>>(input_batch, emb, xbuf);

    // ---- layer 0 ----
    gemm_xp<<<dim3(N3 / 128, (TT * BB) / 128), dim3(256), 0, stream>>>(
        xbuf, W_ih, b_ih, xproj);
    gru_scan<<<dim3(256), dim3(256), 0, stream>>>(
        xproj, W_hh, b_hh, lens,
        xbuf /* ys0 (x_emb is dead now) */, h0, h1,
        out + OUT_FIN /* finals layer 0 */, ctrl, 0u);

    // ---- layer 1 ----
    gemm_xp<<<dim3(N3 / 128, (TT * BB) / 128), dim3(256), 0, stream>>>(
        xbuf, W_ih + (size_t)N3 * EE, b_ih + N3, xproj);
    hipMemsetAsync(h0, 0, 2 * (size_t)BB * EE * sizeof(float), stream);
    gru_scan<<<dim3(256), dim3(256), 0, stream>>>(
        xproj, W_hh + (size_t)N3 * EE, b_hh + N3, lens,
        out + OUT_YS /* ys1 = output x */, h0, h1,
        out + OUT_FIN + (size_t)BB * EE /* finals layer 1 */, ctrl, 512u);
}